// Round 5
// baseline (624.733 us; speedup 1.0000x reference)
//
#include <hip/hip_runtime.h>

#define VOC 49408
#define TD 512
#define DM 768
#define NCOLG 386   // VOC / 128
#define NTILES 772  // VOC / 64
#define PV_S 32

typedef __attribute__((ext_vector_type(8))) short bf16x8;
typedef __attribute__((ext_vector_type(4))) short bf16x4;
typedef __attribute__((ext_vector_type(4))) float f32x4;

__device__ __forceinline__ unsigned short f2bf(float f) {
  unsigned int u = __float_as_uint(f);
  u += 0x7fffu + ((u >> 16) & 1u);   // RNE
  return (unsigned short)(u >> 16);
}

__device__ __forceinline__ void gload16(const void* g, const void* l) {
  __builtin_amdgcn_global_load_lds(
      (const __attribute__((address_space(1))) void*)g,
      (__attribute__((address_space(3))) void*)l, 16, 0, 0);
}

// ---------------------------------------------------------------- K1: proj + normalize
__global__ __launch_bounds__(256) void k_proj(const float* __restrict__ kw,
                                              const float* __restrict__ Wp,
                                              const float* __restrict__ bp,
                                              unsigned short* __restrict__ kwn) {
  __shared__ float row_lds[4 * DM];
  __shared__ float rsum[4][4];
  __shared__ float rinv_s[4];
  const int t = threadIdx.x;
  const int rb = blockIdx.x * 4;
  for (int i = 0; i < 12; ++i) {
    int idx = i * 256 + t;
    row_lds[idx] = kw[(size_t)rb * DM + idx];
  }
  __syncthreads();
  float acc[4][2] = {};
  for (int m = 0; m < DM; ++m) {
    float w0 = Wp[m * TD + t];
    float w1 = Wp[m * TD + t + 256];
#pragma unroll
    for (int r = 0; r < 4; ++r) {
      float kv = row_lds[r * DM + m];
      acc[r][0] = fmaf(kv, w0, acc[r][0]);
      acc[r][1] = fmaf(kv, w1, acc[r][1]);
    }
  }
  const float b0 = bp[t], b1 = bp[t + 256];
  float p[4];
#pragma unroll
  for (int r = 0; r < 4; ++r) {
    acc[r][0] += b0;
    acc[r][1] += b1;
    p[r] = acc[r][0] * acc[r][0] + acc[r][1] * acc[r][1];
  }
#pragma unroll
  for (int off = 32; off; off >>= 1) {
#pragma unroll
    for (int r = 0; r < 4; ++r) p[r] += __shfl_down(p[r], off);
  }
  const int lane = t & 63, wv = t >> 6;
  if (lane == 0) {
#pragma unroll
    for (int r = 0; r < 4; ++r) rsum[r][wv] = p[r];
  }
  __syncthreads();
  if (t < 4) {
    float s = rsum[t][0] + rsum[t][1] + rsum[t][2] + rsum[t][3];
    rinv_s[t] = 1.0f / fmaxf(sqrtf(s), 1e-8f);
  }
  __syncthreads();
#pragma unroll
  for (int r = 0; r < 4; ++r) {
    float ri = rinv_s[r];
    kwn[(size_t)(rb + r) * TD + t] = f2bf(acc[r][0] * ri);
    kwn[(size_t)(rb + r) * TD + t + 256] = f2bf(acc[r][1] * ri);
  }
}

// ---------------------------------------------------------------- K2: reciprocal row norms of W_emb
// grid 12352, block 256 (4 waves, 1 row each)
__global__ __launch_bounds__(256) void k_norms(const float* __restrict__ We,
                                               float* __restrict__ rnormv) {
  const int t = threadIdx.x;
  const int lane = t & 63, w = t >> 6;
  const int v = blockIdx.x * 4 + w;
  const float* rowp = We + (size_t)v * TD;
  float4 a = *(const float4*)(rowp + lane * 8);
  float4 b = *(const float4*)(rowp + lane * 8 + 4);
  float ss = a.x * a.x + a.y * a.y + a.z * a.z + a.w * a.w +
             b.x * b.x + b.y * b.y + b.z * b.z + b.w * b.w;
#pragma unroll
  for (int off = 1; off < 64; off <<= 1) ss += __shfl_xor(ss, off);
  if (lane == 0) rnormv[v] = 1.0f / fmaxf(sqrtf(ss), 1e-8f);
}

// ---------------------------------------------------------------- K2b: one We pass -> embn (normalized) + embT (raw, transposed)
// grid (8 d-tiles, 772 v-tiles), block 256
__global__ __launch_bounds__(256) void k_transpose(const float* __restrict__ We,
                                                   const float* __restrict__ rnormv,
                                                   unsigned short* __restrict__ embn,
                                                   unsigned short* __restrict__ embT) {
  __shared__ unsigned short tile[64 * 72];
  const int t = threadIdx.x;
  const int d0 = blockIdx.x * 64, v0 = blockIdx.y * 64;
#pragma unroll
  for (int i = 0; i < 4; ++i) {
    int vl = i * 16 + (t >> 4), c = t & 15;
    float4 f = *(const float4*)(We + (size_t)(v0 + vl) * TD + d0 + c * 4);
    unsigned short* dst = &tile[vl * 72 + c * 4];
    dst[0] = f2bf(f.x); dst[1] = f2bf(f.y); dst[2] = f2bf(f.z); dst[3] = f2bf(f.w);
    float rn = rnormv[v0 + vl];
    bf16x4 nb;
    nb[0] = (short)f2bf(f.x * rn); nb[1] = (short)f2bf(f.y * rn);
    nb[2] = (short)f2bf(f.z * rn); nb[3] = (short)f2bf(f.w * rn);
    *(bf16x4*)(embn + (size_t)(v0 + vl) * TD + d0 + c * 4) = nb;
  }
  __syncthreads();
#pragma unroll
  for (int p = 0; p < 2; ++p) {
    int dl = p * 32 + (t >> 3), vch = t & 7;
    bf16x8 o;
#pragma unroll
    for (int i = 0; i < 8; ++i) o[i] = (short)tile[(vch * 8 + i) * 72 + dl];
    *(bf16x8*)(embT + (size_t)(d0 + dl) * VOC + v0 + vch * 8) = o;
  }
}

// ---------------------------------------------------------------- K3: cos GEMM + sumexp partials (proven R3 body)
// grid (8 rowg, 386 colg) — rowg fastest so consecutive blocks share the B tile
__global__ __launch_bounds__(256) void k_cos(const unsigned short* __restrict__ kwn,
                                             const unsigned short* __restrict__ embn,
                                             float* __restrict__ cosd,
                                             float* __restrict__ partial) {
  __shared__ unsigned short As[128 * 64];
  __shared__ unsigned short Bs[128 * 64];
  __shared__ float rs[2][128];
  const int t = threadIdx.x;
  const int rowg = blockIdx.x, colg = blockIdx.y;
  const int lane = t & 63, w = t >> 6;
  const int wm = w >> 1, wn = w & 1;
  const int g = lane >> 4, l15 = lane & 15;

  f32x4 acc[4][4];
#pragma unroll
  for (int mi = 0; mi < 4; ++mi)
#pragma unroll
    for (int ni = 0; ni < 4; ++ni)
#pragma unroll
      for (int j = 0; j < 4; ++j) acc[mi][ni][j] = 0.0f;

  const unsigned short* Ab = kwn + (size_t)rowg * 128 * TD + (size_t)(t >> 3) * TD + (t & 7) * 8;
  const unsigned short* Bb = embn + (size_t)colg * 128 * TD + (size_t)(t >> 3) * TD + (t & 7) * 8;

  for (int kt = 0; kt < 8; ++kt) {
#pragma unroll
    for (int i = 0; i < 4; ++i) {
      gload16(Ab + (size_t)(i * 32) * TD + kt * 64, (const void*)(As + i * 2048 + w * 512));
      gload16(Bb + (size_t)(i * 32) * TD + kt * 64, (const void*)(Bs + i * 2048 + w * 512));
    }
    __syncthreads();
#pragma unroll
    for (int ks = 0; ks < 2; ++ks) {
      bf16x8 a[4], b[4];
#pragma unroll
      for (int mi = 0; mi < 4; ++mi)
        a[mi] = *(const bf16x8*)&As[(wm * 64 + mi * 16 + l15) * 64 + ks * 32 + g * 8];
#pragma unroll
      for (int ni = 0; ni < 4; ++ni)
        b[ni] = *(const bf16x8*)&Bs[(wn * 64 + ni * 16 + l15) * 64 + ks * 32 + g * 8];
#pragma unroll
      for (int mi = 0; mi < 4; ++mi)
#pragma unroll
        for (int ni = 0; ni < 4; ++ni)
          acc[mi][ni] =
              __builtin_amdgcn_mfma_f32_16x16x32_bf16(a[mi], b[ni], acc[mi][ni], 0, 0, 0);
    }
    __syncthreads();
  }

  const size_t rowbase = (size_t)rowg * 128 + wm * 64;
  const int colbase = colg * 128 + wn * 64;
#pragma unroll
  for (int mi = 0; mi < 4; ++mi) {
    float es[4] = {0.f, 0.f, 0.f, 0.f};
#pragma unroll
    for (int ni = 0; ni < 4; ++ni) {
#pragma unroll
      for (int j = 0; j < 4; ++j) {
        float c = acc[mi][ni][j];
        cosd[(rowbase + mi * 16 + g * 4 + j) * VOC + colbase + ni * 16 + l15] = c;
        es[j] += __expf(c);
      }
    }
#pragma unroll
    for (int j = 0; j < 4; ++j) {
      float e = es[j];
      e += __shfl_xor(e, 1);
      e += __shfl_xor(e, 2);
      e += __shfl_xor(e, 4);
      e += __shfl_xor(e, 8);
      if (l15 == 0) rs[wn][wm * 64 + mi * 16 + g * 4 + j] = e;
    }
  }
  __syncthreads();
  if (t < 128) {
    float srow = rs[0][t] + rs[1][t];
    partial[(size_t)colg * 1024 + rowg * 128 + t] = srow;
  }
}

// ---------------------------------------------------------------- K3b: denom reduce
__global__ __launch_bounds__(256) void k_denom(const float* __restrict__ partial,
                                               float* __restrict__ rdenom) {
  const int row = blockIdx.x * 256 + threadIdx.x;
  float s = 0.f;
  for (int gI = 0; gI < NCOLG; ++gI) s += partial[(size_t)gI * 1024 + row];
  rdenom[row] = 1.0f / s;
}

// ---------------------------------------------------------------- K4: prob + PV GEMM
// BM=64, BN=512 (full d -> cos read once, prob written once), BK=64.
// grid 512 (XCD-chunked: 16 rowg x 32 splits), block 512 = 8 waves (each 64x64).
// LDS: As padded [64][72] (ds_write-staged, pad kills conflicts), Bs linear [512][64]
// with XOR-swizzled gload source. 74752 B -> 2 blocks/CU; acc=64 VGPR -> 4 waves/SIMD.
__global__ __launch_bounds__(512, 4) void k_pv(const float* __restrict__ cosd,
                                               const unsigned short* __restrict__ embT,
                                               float* __restrict__ prob,
                                               float* __restrict__ kpart) {
  __shared__ unsigned short As[64 * 72];    // 9216 B
  __shared__ unsigned short Bs[512 * 64];   // 65536 B, LDS[r][c8]=G[r][c8^(r&7)]
  const int t = threadIdx.x;
  const int lane = t & 63, w = t >> 6;      // 8 waves; wave w owns d [w*64, +64)
  const int g = lane >> 4, l15 = lane & 15;

  // XCD-chunk: each XCD gets 4 consecutive splits x all 16 rowg (B-window L2 reuse)
  const int id = blockIdx.x;                // 0..511
  const int L = (id & 7) * 64 + (id >> 3);
  const int s = L >> 4;                     // 0..31
  const int rowg = L & 15;                  // 0..15
  const int t0 = s * 24 + (s < 4 ? s : 4);
  const int t1 = t0 + 24 + (s < 4 ? 1 : 0);

  // A-path: thread covers (row ar = t>>3, 8 v at chunk ac = t&7)
  const int ar = t >> 3, ac = t & 7;
  const int grow = rowg * 64 + ar;
  const float* cbase = cosd + (size_t)grow * VOC + ac * 8;
  float* pbase = prob + (size_t)grow * VOC + ac * 8;

  // B staging lane constants
  const int rl = lane >> 3;
  const int bsl = (lane & 7) ^ rl;          // pre-swizzled source chunk

  f32x4 acc[4][4];
#pragma unroll
  for (int mi = 0; mi < 4; ++mi)
#pragma unroll
    for (int ni = 0; ni < 4; ++ni)
#pragma unroll
      for (int j = 0; j < 4; ++j) acc[mi][ni][j] = 0.0f;

  // prefetch first cos chunk
  float4 c0, c1;
  {
    const float* cp = cbase + (size_t)t0 * 64;
    c0 = *(const float4*)cp;
    c1 = *(const float4*)(cp + 4);
  }

  for (int kt = t0; kt < t1; ++kt) {
    const int v0 = kt * 64;
    __syncthreads();  // previous tile's LDS reads done

    // stage B (embT rows 0..511): 8 wave-gloads, linear dest + pre-swizzled src
#pragma unroll
    for (int i = 0; i < 8; ++i) {
      gload16(embT + (size_t)(i * 64 + w * 8 + rl) * VOC + v0 + bsl * 8,
              (const void*)(Bs + (i * 64 + w * 8) * 64));
    }

    // A: p = exp(cos); nontemporal prob store (p handled *rdv later? no: prob needs rdv)
    // prob = exp(cos) * rdenom — rdenom folded here via per-row scalar
    float4 p0, p1;
    p0.x = __expf(c0.x); p0.y = __expf(c0.y); p0.z = __expf(c0.z); p0.w = __expf(c0.w);
    p1.x = __expf(c1.x); p1.y = __expf(c1.y); p1.z = __expf(c1.z); p1.w = __expf(c1.w);
    bf16x8 a8;
    a8[0] = (short)f2bf(p0.x); a8[1] = (short)f2bf(p0.y);
    a8[2] = (short)f2bf(p0.z); a8[3] = (short)f2bf(p0.w);
    a8[4] = (short)f2bf(p1.x); a8[5] = (short)f2bf(p1.y);
    a8[6] = (short)f2bf(p1.z); a8[7] = (short)f2bf(p1.w);
    *(bf16x8*)&As[ar * 72 + ac * 8] = a8;

    // prefetch next cos chunk (overlaps B-drain + MFMA)
    if (kt + 1 < t1) {
      const float* cp = cbase + (size_t)(kt + 1) * 64;
      c0 = *(const float4*)cp;
      c1 = *(const float4*)(cp + 4);
    }

    __syncthreads();  // A ds_writes + B gloads complete

    // MFMA: rows mi*16+l15 (64), d = w*64 + ni*16 + l15
#pragma unroll
    for (int ks = 0; ks < 2; ++ks) {
      bf16x8 a[4];
#pragma unroll
      for (int mi = 0; mi < 4; ++mi)
        a[mi] = *(const bf16x8*)&As[(mi * 16 + l15) * 72 + ks * 32 + g * 8];
      const int ch = (((ks * 4 + g) ^ (l15 & 7)) << 3);
#pragma unroll
      for (int ni = 0; ni < 4; ++ni) {
        bf16x8 b = *(const bf16x8*)&Bs[(w * 64 + ni * 16 + l15) * 64 + ch];
#pragma unroll
        for (int mi = 0; mi < 4; ++mi)
          acc[mi][ni] = __builtin_amdgcn_mfma_f32_16x16x32_bf16(a[mi], b, acc[mi][ni], 0, 0, 0);
      }
    }

    // prob store (unnormalized exp held in p; normalize with rdv in k_kwout? NO —
    // prob is an OUTPUT: must be exp*rdenom. Store exp now scaled in k_prob pass is
    // extra traffic; instead scale here with the per-row reciprocal.)
    {
      // per-thread row-constant reciprocal: loaded once (uniform across kt)
      // (kept outside-loop value; see rdv below)
    }
    __builtin_nontemporal_store(p0.x, pbase + v0 + 0);
    __builtin_nontemporal_store(p0.y, pbase + v0 + 1);
    __builtin_nontemporal_store(p0.z, pbase + v0 + 2);
    __builtin_nontemporal_store(p0.w, pbase + v0 + 3);
    __builtin_nontemporal_store(p1.x, pbase + v0 + 4);
    __builtin_nontemporal_store(p1.y, pbase + v0 + 5);
    __builtin_nontemporal_store(p1.z, pbase + v0 + 6);
    __builtin_nontemporal_store(p1.w, pbase + v0 + 7);
  }

  // epilogue: kpart[s][row][d] (unnormalized; rdv applied in k_kwout)
#pragma unroll
  for (int mi = 0; mi < 4; ++mi)
#pragma unroll
    for (int ni = 0; ni < 4; ++ni)
#pragma unroll
      for (int j = 0; j < 4; ++j)
        kpart[((size_t)s * 1024 + rowg * 64 + mi * 16 + g * 4 + j) * TD +
              w * 64 + ni * 16 + l15] = acc[mi][ni][j];
}

// ---------------------------------------------------------------- K4b: prob normalize (in-place scale)
// prob currently holds exp(cos); scale by rdenom[row]. grid 2048, block 256, float4.
__global__ __launch_bounds__(256) void k_pnorm(float* __restrict__ prob,
                                               const float* __restrict__ rdenom) {
  const size_t gid = (size_t)blockIdx.x * 256 + threadIdx.x;
  const size_t nvec = (size_t)1024 * VOC / 4;  // 12,648,448
  for (size_t i = gid; i < nvec; i += 2048 * 256) {
    const int row = (int)(i * 4 / VOC);
    float4 v = *(const float4*)(prob + i * 4);
    const float rdv = rdenom[row];
    v.x *= rdv; v.y *= rdv; v.z *= rdv; v.w *= rdv;
    *(float4*)(prob + i * 4) = v;
  }
}

// ---------------------------------------------------------------- K5: kw_out reduce (+rdv)
__global__ __launch_bounds__(256) void k_kwout(const float* __restrict__ kpart,
                                               const float* __restrict__ rdenom,
                                               float* __restrict__ outp) {
  const int gid = blockIdx.x * 256 + threadIdx.x;   // 0..131071, 4 elems each
  const int row = gid >> 7;
  float4 s = {0.f, 0.f, 0.f, 0.f};
#pragma unroll
  for (int sp = 0; sp < PV_S; ++sp) {
    float4 v = *(const float4*)(kpart + (size_t)sp * 524288 + gid * 4);
    s.x += v.x; s.y += v.y; s.z += v.z; s.w += v.w;
  }
  const float rdv = rdenom[row];
  float4 o;
  o.x = s.x * rdv; o.y = s.y * rdv; o.z = s.z * rdv; o.w = s.w * rdv;
  *(float4*)(outp + gid * 4) = o;
}

extern "C" void kernel_launch(void* const* d_in, const int* in_sizes, int n_in,
                              void* d_out, int out_size, void* d_ws, size_t ws_size,
                              hipStream_t stream) {
  const float* kw = (const float*)d_in[0];
  const float* Wp = (const float*)d_in[1];
  const float* bp = (const float*)d_in[2];
  const float* We = (const float*)d_in[3];
  float* out = (float*)d_out;
  char* ws = (char*)d_ws;

  unsigned short* embT = (unsigned short*)ws;                       // 50,593,792
  unsigned short* embn = (unsigned short*)(ws + 50593792);          // 50,593,792
  unsigned short* kwn = (unsigned short*)(ws + 101187584);          // 1,048,576
  float* rnormv = (float*)(ws + 102236160);                         // 197,632
  float* partial = (float*)(ws + 102433792);                        // 1,581,056
  float* rdenom = (float*)(ws + 104014848);                         // 4,096
  float* kpart = (float*)(ws + 104018944);                          // 67,108,864

  float* kwout = out;
  float* prob = out + 524288;
  float* cosd = out + 51118080;

  hipLaunchKernelGGL(k_proj, dim3(256), dim3(256), 0, stream, kw, Wp, bp, kwn);
  hipLaunchKernelGGL(k_norms, dim3(12352), dim3(256), 0, stream, We, rnormv);
  hipLaunchKernelGGL(k_transpose, dim3(8, 772), dim3(256), 0, stream, We, rnormv, embn, embT);
  hipLaunchKernelGGL(k_cos, dim3(8, NCOLG), dim3(256), 0, stream, kwn, embn, cosd, partial);
  hipLaunchKernelGGL(k_denom, dim3(4), dim3(256), 0, stream, partial, rdenom);
  hipLaunchKernelGGL(k_pv, dim3(512), dim3(512), 0, stream, cosd, embT, prob, kpart);
  hipLaunchKernelGGL(k_pnorm, dim3(2048), dim3(256), 0, stream, prob, rdenom);
  hipLaunchKernelGGL(k_kwout, dim3(512), dim3(256), 0, stream, kpart, rdenom, kwout);
}

// Round 6
// 520.101 us; speedup vs baseline: 1.2012x; 1.2012x over previous
//
#include <hip/hip_runtime.h>

#define VOC 49408
#define TD 512
#define DM 768
#define NCOLG 386   // VOC / 128
#define NTILES 772  // VOC / 64
#define PV_S 32

typedef __attribute__((ext_vector_type(8))) short bf16x8;
typedef __attribute__((ext_vector_type(4))) short bf16x4;
typedef __attribute__((ext_vector_type(4))) float f32x4;

__device__ __forceinline__ unsigned short f2bf(float f) {
  unsigned int u = __float_as_uint(f);
  u += 0x7fffu + ((u >> 16) & 1u);   // RNE
  return (unsigned short)(u >> 16);
}

__device__ __forceinline__ void gload16(const void* g, const void* l) {
  __builtin_amdgcn_global_load_lds(
      (const __attribute__((address_space(1))) void*)g,
      (__attribute__((address_space(3))) void*)l, 16, 0, 0);
}

// ---------------------------------------------------------------- K1: proj + normalize
__global__ __launch_bounds__(256) void k_proj(const float* __restrict__ kw,
                                              const float* __restrict__ Wp,
                                              const float* __restrict__ bp,
                                              unsigned short* __restrict__ kwn) {
  __shared__ float row_lds[4 * DM];
  __shared__ float rsum[4][4];
  __shared__ float rinv_s[4];
  const int t = threadIdx.x;
  const int rb = blockIdx.x * 4;
  for (int i = 0; i < 12; ++i) {
    int idx = i * 256 + t;
    row_lds[idx] = kw[(size_t)rb * DM + idx];
  }
  __syncthreads();
  float acc[4][2] = {};
  for (int m = 0; m < DM; ++m) {
    float w0 = Wp[m * TD + t];
    float w1 = Wp[m * TD + t + 256];
#pragma unroll
    for (int r = 0; r < 4; ++r) {
      float kv = row_lds[r * DM + m];
      acc[r][0] = fmaf(kv, w0, acc[r][0]);
      acc[r][1] = fmaf(kv, w1, acc[r][1]);
    }
  }
  const float b0 = bp[t], b1 = bp[t + 256];
  float p[4];
#pragma unroll
  for (int r = 0; r < 4; ++r) {
    acc[r][0] += b0;
    acc[r][1] += b1;
    p[r] = acc[r][0] * acc[r][0] + acc[r][1] * acc[r][1];
  }
#pragma unroll
  for (int off = 32; off; off >>= 1) {
#pragma unroll
    for (int r = 0; r < 4; ++r) p[r] += __shfl_down(p[r], off);
  }
  const int lane = t & 63, wv = t >> 6;
  if (lane == 0) {
#pragma unroll
    for (int r = 0; r < 4; ++r) rsum[r][wv] = p[r];
  }
  __syncthreads();
  if (t < 4) {
    float s = rsum[t][0] + rsum[t][1] + rsum[t][2] + rsum[t][3];
    rinv_s[t] = 1.0f / fmaxf(sqrtf(s), 1e-8f);
  }
  __syncthreads();
#pragma unroll
  for (int r = 0; r < 4; ++r) {
    float ri = rinv_s[r];
    kwn[(size_t)(rb + r) * TD + t] = f2bf(acc[r][0] * ri);
    kwn[(size_t)(rb + r) * TD + t + 256] = f2bf(acc[r][1] * ri);
  }
}

// ---------------------------------------------------------------- K2: reciprocal row norms of W_emb
__global__ __launch_bounds__(256) void k_norms(const float* __restrict__ We,
                                               float* __restrict__ rnormv) {
  const int t = threadIdx.x;
  const int lane = t & 63, w = t >> 6;
  const int v = blockIdx.x * 4 + w;
  const float* rowp = We + (size_t)v * TD;
  float4 a = *(const float4*)(rowp + lane * 8);
  float4 b = *(const float4*)(rowp + lane * 8 + 4);
  float ss = a.x * a.x + a.y * a.y + a.z * a.z + a.w * a.w +
             b.x * b.x + b.y * b.y + b.z * b.z + b.w * b.w;
#pragma unroll
  for (int off = 1; off < 64; off <<= 1) ss += __shfl_xor(ss, off);
  if (lane == 0) rnormv[v] = 1.0f / fmaxf(sqrtf(ss), 1e-8f);
}

// ---------------------------------------------------------------- K2b: one We pass -> embn (normalized) + embT (raw^T)
__global__ __launch_bounds__(256) void k_transpose(const float* __restrict__ We,
                                                   const float* __restrict__ rnormv,
                                                   unsigned short* __restrict__ embn,
                                                   unsigned short* __restrict__ embT) {
  __shared__ unsigned short tile[64 * 72];
  const int t = threadIdx.x;
  const int d0 = blockIdx.x * 64, v0 = blockIdx.y * 64;
#pragma unroll
  for (int i = 0; i < 4; ++i) {
    int vl = i * 16 + (t >> 4), c = t & 15;
    float4 f = *(const float4*)(We + (size_t)(v0 + vl) * TD + d0 + c * 4);
    unsigned short* dst = &tile[vl * 72 + c * 4];
    dst[0] = f2bf(f.x); dst[1] = f2bf(f.y); dst[2] = f2bf(f.z); dst[3] = f2bf(f.w);
    float rn = rnormv[v0 + vl];
    bf16x4 nb;
    nb[0] = (short)f2bf(f.x * rn); nb[1] = (short)f2bf(f.y * rn);
    nb[2] = (short)f2bf(f.z * rn); nb[3] = (short)f2bf(f.w * rn);
    *(bf16x4*)(embn + (size_t)(v0 + vl) * TD + d0 + c * 4) = nb;
  }
  __syncthreads();
#pragma unroll
  for (int p = 0; p < 2; ++p) {
    int dl = p * 32 + (t >> 3), vch = t & 7;
    bf16x8 o;
#pragma unroll
    for (int i = 0; i < 8; ++i) o[i] = (short)tile[(vch * 8 + i) * 72 + dl];
    *(bf16x8*)(embT + (size_t)(d0 + dl) * VOC + v0 + vch * 8) = o;
  }
}

// ---------------------------------------------------------------- K3: cos GEMM + sumexp partials (proven R3 body)
__global__ __launch_bounds__(256) void k_cos(const unsigned short* __restrict__ kwn,
                                             const unsigned short* __restrict__ embn,
                                             float* __restrict__ cosd,
                                             float* __restrict__ partial) {
  __shared__ unsigned short As[128 * 64];
  __shared__ unsigned short Bs[128 * 64];
  __shared__ float rs[2][128];
  const int t = threadIdx.x;
  const int rowg = blockIdx.x, colg = blockIdx.y;
  const int lane = t & 63, w = t >> 6;
  const int wm = w >> 1, wn = w & 1;
  const int g = lane >> 4, l15 = lane & 15;

  f32x4 acc[4][4];
#pragma unroll
  for (int mi = 0; mi < 4; ++mi)
#pragma unroll
    for (int ni = 0; ni < 4; ++ni)
#pragma unroll
      for (int j = 0; j < 4; ++j) acc[mi][ni][j] = 0.0f;

  const unsigned short* Ab = kwn + (size_t)rowg * 128 * TD + (size_t)(t >> 3) * TD + (t & 7) * 8;
  const unsigned short* Bb = embn + (size_t)colg * 128 * TD + (size_t)(t >> 3) * TD + (t & 7) * 8;

  for (int kt = 0; kt < 8; ++kt) {
#pragma unroll
    for (int i = 0; i < 4; ++i) {
      gload16(Ab + (size_t)(i * 32) * TD + kt * 64, (const void*)(As + i * 2048 + w * 512));
      gload16(Bb + (size_t)(i * 32) * TD + kt * 64, (const void*)(Bs + i * 2048 + w * 512));
    }
    __syncthreads();
#pragma unroll
    for (int ks = 0; ks < 2; ++ks) {
      bf16x8 a[4], b[4];
#pragma unroll
      for (int mi = 0; mi < 4; ++mi)
        a[mi] = *(const bf16x8*)&As[(wm * 64 + mi * 16 + l15) * 64 + ks * 32 + g * 8];
#pragma unroll
      for (int ni = 0; ni < 4; ++ni)
        b[ni] = *(const bf16x8*)&Bs[(wn * 64 + ni * 16 + l15) * 64 + ks * 32 + g * 8];
#pragma unroll
      for (int mi = 0; mi < 4; ++mi)
#pragma unroll
        for (int ni = 0; ni < 4; ++ni)
          acc[mi][ni] =
              __builtin_amdgcn_mfma_f32_16x16x32_bf16(a[mi], b[ni], acc[mi][ni], 0, 0, 0);
    }
    __syncthreads();
  }

  const size_t rowbase = (size_t)rowg * 128 + wm * 64;
  const int colbase = colg * 128 + wn * 64;
#pragma unroll
  for (int mi = 0; mi < 4; ++mi) {
    float es[4] = {0.f, 0.f, 0.f, 0.f};
#pragma unroll
    for (int ni = 0; ni < 4; ++ni) {
#pragma unroll
      for (int j = 0; j < 4; ++j) {
        float c = acc[mi][ni][j];
        cosd[(rowbase + mi * 16 + g * 4 + j) * VOC + colbase + ni * 16 + l15] = c;
        es[j] += __expf(c);
      }
    }
#pragma unroll
    for (int j = 0; j < 4; ++j) {
      float e = es[j];
      e += __shfl_xor(e, 1);
      e += __shfl_xor(e, 2);
      e += __shfl_xor(e, 4);
      e += __shfl_xor(e, 8);
      if (l15 == 0) rs[wn][wm * 64 + mi * 16 + g * 4 + j] = e;
    }
  }
  __syncthreads();
  if (t < 128) {
    float srow = rs[0][t] + rs[1][t];
    partial[(size_t)colg * 1024 + rowg * 128 + t] = srow;
  }
}

// ---------------------------------------------------------------- K3b: denom reduce
__global__ __launch_bounds__(256) void k_denom(const float* __restrict__ partial,
                                               float* __restrict__ rdenom) {
  const int row = blockIdx.x * 256 + threadIdx.x;
  float s = 0.f;
  for (int gI = 0; gI < NCOLG; ++gI) s += partial[(size_t)gI * 1024 + row];
  rdenom[row] = 1.0f / s;
}

// ---------------------------------------------------------------- K4: prob + PV GEMM
// BM=64, BN=512 (cos read ONCE, prob written ONCE), BK=64. grid 512 = 16 rowg x 32
// splits (XCD-chunked), block 256 = 4 waves; wave w owns d [w*128,+128), acc[4][8].
// A = bf16(exp(cos)*rdv) ds_write-staged into padded [64][72]; prob = same value f32.
// B = embT gload16, linear LDS + pre-swizzled source. LDS 73 KB -> 2 blocks/CU.
__global__ __launch_bounds__(256, 2) void k_pv(const float* __restrict__ cosd,
                                               const unsigned short* __restrict__ embT,
                                               const float* __restrict__ rdenom,
                                               float* __restrict__ prob,
                                               float* __restrict__ kpart) {
  __shared__ unsigned short As[64 * 72];    // 9216 B, unswizzled (pad 72 breaks conflicts)
  __shared__ unsigned short Bs[512 * 64];   // 65536 B, LDS[r][c8]=G[r][c8^(r&7)]
  const int t = threadIdx.x;
  const int lane = t & 63, w = t >> 6;
  const int g = lane >> 4, l15 = lane & 15;

  const int id = blockIdx.x;                // 0..511
  const int L = (id & 7) * 64 + (id >> 3);  // XCD-chunked (bijective: 512=8*64)
  const int s = L >> 4;                     // 0..31
  const int rowg = L & 15;                  // 0..15
  const int t0 = s * 24 + (s < 4 ? s : 4);
  const int t1 = t0 + 24 + (s < 4 ? 1 : 0);

  // A-path: thread owns row ar (0..63), 16-float chunk ac (0..3)
  const int ar = t >> 2, ac = t & 3;
  const int grow = rowg * 64 + ar;
  const float rdv = rdenom[grow];
  const float* cbase = cosd + (size_t)grow * VOC + ac * 16;
  float* pbase = prob + (size_t)grow * VOC + ac * 16;
  const int aoff = ar * 72 + ac * 16;       // ushort offset (16B-aligned: 144B rows)

  // B staging lane constants
  const int rl = lane >> 3;
  const int bsl = (lane & 7) ^ rl;          // pre-swizzled source chunk

  f32x4 acc[4][8];
#pragma unroll
  for (int mi = 0; mi < 4; ++mi)
#pragma unroll
    for (int ni = 0; ni < 8; ++ni)
#pragma unroll
      for (int j = 0; j < 4; ++j) acc[mi][ni][j] = 0.0f;

  // prefetch first cos chunk (16 floats)
  float4 c0, c1, c2, c3;
  {
    const float* cp = cbase + (size_t)t0 * 64;
    c0 = *(const float4*)(cp);
    c1 = *(const float4*)(cp + 4);
    c2 = *(const float4*)(cp + 8);
    c3 = *(const float4*)(cp + 12);
  }

  for (int kt = t0; kt < t1; ++kt) {
    const int v0 = kt * 64;
    __syncthreads();  // previous tile's LDS reads done

    // stage B (embT d-rows 0..511): 16 wave-gloads
#pragma unroll
    for (int i = 0; i < 16; ++i) {
      gload16(embT + (size_t)(i * 32 + w * 8 + rl) * VOC + v0 + bsl * 8,
              (const void*)(Bs + (i * 32 + w * 8) * 64));
    }

    // A: p = exp(cos)*rdv -> prob (float4) + As (bf16)
    float4 p0, p1, p2, p3;
    p0.x = __expf(c0.x) * rdv; p0.y = __expf(c0.y) * rdv;
    p0.z = __expf(c0.z) * rdv; p0.w = __expf(c0.w) * rdv;
    p1.x = __expf(c1.x) * rdv; p1.y = __expf(c1.y) * rdv;
    p1.z = __expf(c1.z) * rdv; p1.w = __expf(c1.w) * rdv;
    p2.x = __expf(c2.x) * rdv; p2.y = __expf(c2.y) * rdv;
    p2.z = __expf(c2.z) * rdv; p2.w = __expf(c2.w) * rdv;
    p3.x = __expf(c3.x) * rdv; p3.y = __expf(c3.y) * rdv;
    p3.z = __expf(c3.z) * rdv; p3.w = __expf(c3.w) * rdv;
    *(float4*)(pbase + v0) = p0;
    *(float4*)(pbase + v0 + 4) = p1;
    *(float4*)(pbase + v0 + 8) = p2;
    *(float4*)(pbase + v0 + 12) = p3;
    bf16x8 a8;
    a8[0] = (short)f2bf(p0.x); a8[1] = (short)f2bf(p0.y);
    a8[2] = (short)f2bf(p0.z); a8[3] = (short)f2bf(p0.w);
    a8[4] = (short)f2bf(p1.x); a8[5] = (short)f2bf(p1.y);
    a8[6] = (short)f2bf(p1.z); a8[7] = (short)f2bf(p1.w);
    *(bf16x8*)&As[aoff] = a8;
    a8[0] = (short)f2bf(p2.x); a8[1] = (short)f2bf(p2.y);
    a8[2] = (short)f2bf(p2.z); a8[3] = (short)f2bf(p2.w);
    a8[4] = (short)f2bf(p3.x); a8[5] = (short)f2bf(p3.y);
    a8[6] = (short)f2bf(p3.z); a8[7] = (short)f2bf(p3.w);
    *(bf16x8*)&As[aoff + 8] = a8;

    // prefetch next cos chunk (overlaps the barrier's vmcnt drain)
    if (kt + 1 < t1) {
      const float* cp = cbase + (size_t)(kt + 1) * 64;
      c0 = *(const float4*)(cp);
      c1 = *(const float4*)(cp + 4);
      c2 = *(const float4*)(cp + 8);
      c3 = *(const float4*)(cp + 12);
    }

    __syncthreads();  // A ds_writes + B gloads complete

    // MFMA: rows mi*16+l15 (64), d = w*128 + ni*16 + l15
#pragma unroll
    for (int ks = 0; ks < 2; ++ks) {
      bf16x8 a[4];
#pragma unroll
      for (int mi = 0; mi < 4; ++mi)
        a[mi] = *(const bf16x8*)&As[(mi * 16 + l15) * 72 + ks * 32 + g * 8];
      const int ch = (((ks * 4 + g) ^ (l15 & 7)) << 3);
#pragma unroll
      for (int ni = 0; ni < 8; ++ni) {
        bf16x8 b = *(const bf16x8*)&Bs[(w * 128 + ni * 16 + l15) * 64 + ch];
#pragma unroll
        for (int mi = 0; mi < 4; ++mi)
          acc[mi][ni] = __builtin_amdgcn_mfma_f32_16x16x32_bf16(a[mi], b, acc[mi][ni], 0, 0, 0);
      }
    }
  }

  // epilogue: kpart[s][row][d] (already normalized — A carried rdv)
#pragma unroll
  for (int mi = 0; mi < 4; ++mi)
#pragma unroll
    for (int ni = 0; ni < 8; ++ni)
#pragma unroll
      for (int j = 0; j < 4; ++j)
        kpart[((size_t)s * 1024 + rowg * 64 + mi * 16 + g * 4 + j) * TD +
              w * 128 + ni * 16 + l15] = acc[mi][ni][j];
}

// ---------------------------------------------------------------- K5: kw_out reduce (pure sum)
__global__ __launch_bounds__(256) void k_kwout(const float* __restrict__ kpart,
                                               float* __restrict__ outp) {
  const int gid = blockIdx.x * 256 + threadIdx.x;   // 131072 threads x 4 elems
  float4 s = {0.f, 0.f, 0.f, 0.f};
#pragma unroll
  for (int sp = 0; sp < PV_S; ++sp) {
    float4 v = *(const float4*)(kpart + (size_t)sp * 524288 + gid * 4);
    s.x += v.x; s.y += v.y; s.z += v.z; s.w += v.w;
  }
  *(float4*)(outp + gid * 4) = s;
}

extern "C" void kernel_launch(void* const* d_in, const int* in_sizes, int n_in,
                              void* d_out, int out_size, void* d_ws, size_t ws_size,
                              hipStream_t stream) {
  const float* kw = (const float*)d_in[0];
  const float* Wp = (const float*)d_in[1];
  const float* bp = (const float*)d_in[2];
  const float* We = (const float*)d_in[3];
  float* out = (float*)d_out;
  char* ws = (char*)d_ws;

  unsigned short* embT = (unsigned short*)ws;                       // 50,593,792
  unsigned short* embn = (unsigned short*)(ws + 50593792);          // 50,593,792
  unsigned short* kwn = (unsigned short*)(ws + 101187584);          // 1,048,576
  float* rnormv = (float*)(ws + 102236160);                         // 197,632
  float* partial = (float*)(ws + 102433792);                        // 1,581,056
  float* rdenom = (float*)(ws + 104014848);                         // 4,096
  float* kpart = (float*)(ws + 104018944);                          // 67,108,864

  float* kwout = out;
  float* prob = out + 524288;
  float* cosd = out + 51118080;

  hipLaunchKernelGGL(k_proj, dim3(256), dim3(256), 0, stream, kw, Wp, bp, kwn);
  hipLaunchKernelGGL(k_norms, dim3(12352), dim3(256), 0, stream, We, rnormv);
  hipLaunchKernelGGL(k_transpose, dim3(8, 772), dim3(256), 0, stream, We, rnormv, embn, embT);
  hipLaunchKernelGGL(k_cos, dim3(8, NCOLG), dim3(256), 0, stream, kwn, embn, cosd, partial);
  hipLaunchKernelGGL(k_denom, dim3(4), dim3(256), 0, stream, partial, rdenom);
  hipLaunchKernelGGL(k_pv, dim3(512), dim3(256), 0, stream, cosd, embT, rdenom, prob, kpart);
  hipLaunchKernelGGL(k_kwout, dim3(512), dim3(256), 0, stream, kpart, kwout);
}

// Round 7
// 493.789 us; speedup vs baseline: 1.2652x; 1.0533x over previous
//
#include <hip/hip_runtime.h>

#define VOC 49408
#define TD 512
#define DM 768
#define NCOLG 386   // VOC / 128
#define NTILES 772  // VOC / 64
#define PV_S 32

typedef __attribute__((ext_vector_type(8))) short bf16x8;
typedef __attribute__((ext_vector_type(4))) short bf16x4;
typedef __attribute__((ext_vector_type(4))) float f32x4;

__device__ __forceinline__ unsigned short f2bf(float f) {
  unsigned int u = __float_as_uint(f);
  u += 0x7fffu + ((u >> 16) & 1u);   // RNE
  return (unsigned short)(u >> 16);
}

__device__ __forceinline__ void gload16(const void* g, const void* l) {
  __builtin_amdgcn_global_load_lds(
      (const __attribute__((address_space(1))) void*)g,
      (__attribute__((address_space(3))) void*)l, 16, 0, 0);
}

// ---------------------------------------------------------------- K1: proj + normalize
__global__ __launch_bounds__(256) void k_proj(const float* __restrict__ kw,
                                              const float* __restrict__ Wp,
                                              const float* __restrict__ bp,
                                              unsigned short* __restrict__ kwn) {
  __shared__ float row_lds[4 * DM];
  __shared__ float rsum[4][4];
  __shared__ float rinv_s[4];
  const int t = threadIdx.x;
  const int rb = blockIdx.x * 4;
  for (int i = 0; i < 12; ++i) {
    int idx = i * 256 + t;
    row_lds[idx] = kw[(size_t)rb * DM + idx];
  }
  __syncthreads();
  float acc[4][2] = {};
  for (int m = 0; m < DM; ++m) {
    float w0 = Wp[m * TD + t];
    float w1 = Wp[m * TD + t + 256];
#pragma unroll
    for (int r = 0; r < 4; ++r) {
      float kv = row_lds[r * DM + m];
      acc[r][0] = fmaf(kv, w0, acc[r][0]);
      acc[r][1] = fmaf(kv, w1, acc[r][1]);
    }
  }
  const float b0 = bp[t], b1 = bp[t + 256];
  float p[4];
#pragma unroll
  for (int r = 0; r < 4; ++r) {
    acc[r][0] += b0;
    acc[r][1] += b1;
    p[r] = acc[r][0] * acc[r][0] + acc[r][1] * acc[r][1];
  }
#pragma unroll
  for (int off = 32; off; off >>= 1) {
#pragma unroll
    for (int r = 0; r < 4; ++r) p[r] += __shfl_down(p[r], off);
  }
  const int lane = t & 63, wv = t >> 6;
  if (lane == 0) {
#pragma unroll
    for (int r = 0; r < 4; ++r) rsum[r][wv] = p[r];
  }
  __syncthreads();
  if (t < 4) {
    float s = rsum[t][0] + rsum[t][1] + rsum[t][2] + rsum[t][3];
    rinv_s[t] = 1.0f / fmaxf(sqrtf(s), 1e-8f);
  }
  __syncthreads();
#pragma unroll
  for (int r = 0; r < 4; ++r) {
    float ri = rinv_s[r];
    kwn[(size_t)(rb + r) * TD + t] = f2bf(acc[r][0] * ri);
    kwn[(size_t)(rb + r) * TD + t + 256] = f2bf(acc[r][1] * ri);
  }
}

// ---------------------------------------------------------------- K2: reciprocal row norms of W_emb
__global__ __launch_bounds__(256) void k_norms(const float* __restrict__ We,
                                               float* __restrict__ rnormv) {
  const int t = threadIdx.x;
  const int lane = t & 63, w = t >> 6;
  const int v = blockIdx.x * 4 + w;
  const float* rowp = We + (size_t)v * TD;
  float4 a = *(const float4*)(rowp + lane * 8);
  float4 b = *(const float4*)(rowp + lane * 8 + 4);
  float ss = a.x * a.x + a.y * a.y + a.z * a.z + a.w * a.w +
             b.x * b.x + b.y * b.y + b.z * b.z + b.w * b.w;
#pragma unroll
  for (int off = 1; off < 64; off <<= 1) ss += __shfl_xor(ss, off);
  if (lane == 0) rnormv[v] = 1.0f / fmaxf(sqrtf(ss), 1e-8f);
}

// ---------------------------------------------------------------- K2b: one We pass -> embn (normalized) + embT (raw^T)
// grid 6176 linear; XCD-chunked decode so same-v0 blocks colocate per XCD.
__global__ __launch_bounds__(256) void k_transpose(const float* __restrict__ We,
                                                   const float* __restrict__ rnormv,
                                                   unsigned short* __restrict__ embn,
                                                   unsigned short* __restrict__ embT) {
  __shared__ unsigned short tile[64 * 72];
  const int t = threadIdx.x;
  const int id = blockIdx.x;                 // 0..6175
  const int gslot = (id & 7) * 772 + (id >> 3);
  const int v0 = (gslot >> 3) * 64;
  const int d0 = (gslot & 7) * 64;
#pragma unroll
  for (int i = 0; i < 4; ++i) {
    int vl = i * 16 + (t >> 4), c = t & 15;
    float4 f = *(const float4*)(We + (size_t)(v0 + vl) * TD + d0 + c * 4);
    unsigned short* dst = &tile[vl * 72 + c * 4];
    dst[0] = f2bf(f.x); dst[1] = f2bf(f.y); dst[2] = f2bf(f.z); dst[3] = f2bf(f.w);
    float rn = rnormv[v0 + vl];
    bf16x4 nb;
    nb[0] = (short)f2bf(f.x * rn); nb[1] = (short)f2bf(f.y * rn);
    nb[2] = (short)f2bf(f.z * rn); nb[3] = (short)f2bf(f.w * rn);
    *(bf16x4*)(embn + (size_t)(v0 + vl) * TD + d0 + c * 4) = nb;
  }
  __syncthreads();
#pragma unroll
  for (int p = 0; p < 2; ++p) {
    int dl = p * 32 + (t >> 3), vch = t & 7;
    bf16x8 o;
#pragma unroll
    for (int i = 0; i < 8; ++i) o[i] = (short)tile[(vch * 8 + i) * 72 + dl];
    *(bf16x8*)(embT + (size_t)(d0 + dl) * VOC + v0 + vch * 8) = o;
  }
}

// ---------------------------------------------------------------- K3: cos GEMM + sumexp partials
// grid 3088 linear; XCD-chunked decode: each XCD owns a contiguous colg range with
// all 8 rowg co-resident -> B-tile staging becomes same-XCD L2 hits (was 8x L3).
__global__ __launch_bounds__(256) void k_cos(const unsigned short* __restrict__ kwn,
                                             const unsigned short* __restrict__ embn,
                                             float* __restrict__ cosd,
                                             float* __restrict__ partial) {
  __shared__ unsigned short As[128 * 64];
  __shared__ unsigned short Bs[128 * 64];
  __shared__ float rs[2][128];
  const int t = threadIdx.x;
  const int id = blockIdx.x;                 // 0..3087
  const int gslot = (id & 7) * 386 + (id >> 3);
  const int colg = gslot >> 3;               // 0..385
  const int rowg = gslot & 7;                // 0..7
  const int lane = t & 63, w = t >> 6;
  const int wm = w >> 1, wn = w & 1;
  const int g = lane >> 4, l15 = lane & 15;

  f32x4 acc[4][4];
#pragma unroll
  for (int mi = 0; mi < 4; ++mi)
#pragma unroll
    for (int ni = 0; ni < 4; ++ni)
#pragma unroll
      for (int j = 0; j < 4; ++j) acc[mi][ni][j] = 0.0f;

  const unsigned short* Ab = kwn + (size_t)rowg * 128 * TD + (size_t)(t >> 3) * TD + (t & 7) * 8;
  const unsigned short* Bb = embn + (size_t)colg * 128 * TD + (size_t)(t >> 3) * TD + (t & 7) * 8;

  for (int kt = 0; kt < 8; ++kt) {
#pragma unroll
    for (int i = 0; i < 4; ++i) {
      gload16(Ab + (size_t)(i * 32) * TD + kt * 64, (const void*)(As + i * 2048 + w * 512));
      gload16(Bb + (size_t)(i * 32) * TD + kt * 64, (const void*)(Bs + i * 2048 + w * 512));
    }
    __syncthreads();
#pragma unroll
    for (int ks = 0; ks < 2; ++ks) {
      bf16x8 a[4], b[4];
#pragma unroll
      for (int mi = 0; mi < 4; ++mi)
        a[mi] = *(const bf16x8*)&As[(wm * 64 + mi * 16 + l15) * 64 + ks * 32 + g * 8];
#pragma unroll
      for (int ni = 0; ni < 4; ++ni)
        b[ni] = *(const bf16x8*)&Bs[(wn * 64 + ni * 16 + l15) * 64 + ks * 32 + g * 8];
#pragma unroll
      for (int mi = 0; mi < 4; ++mi)
#pragma unroll
        for (int ni = 0; ni < 4; ++ni)
          acc[mi][ni] =
              __builtin_amdgcn_mfma_f32_16x16x32_bf16(a[mi], b[ni], acc[mi][ni], 0, 0, 0);
    }
    __syncthreads();
  }

  const size_t rowbase = (size_t)rowg * 128 + wm * 64;
  const int colbase = colg * 128 + wn * 64;
#pragma unroll
  for (int mi = 0; mi < 4; ++mi) {
    float es[4] = {0.f, 0.f, 0.f, 0.f};
#pragma unroll
    for (int ni = 0; ni < 4; ++ni) {
#pragma unroll
      for (int j = 0; j < 4; ++j) {
        float c = acc[mi][ni][j];
        cosd[(rowbase + mi * 16 + g * 4 + j) * VOC + colbase + ni * 16 + l15] = c;
        es[j] += __expf(c);
      }
    }
#pragma unroll
    for (int j = 0; j < 4; ++j) {
      float e = es[j];
      e += __shfl_xor(e, 1);
      e += __shfl_xor(e, 2);
      e += __shfl_xor(e, 4);
      e += __shfl_xor(e, 8);
      if (l15 == 0) rs[wn][wm * 64 + mi * 16 + g * 4 + j] = e;
    }
  }
  __syncthreads();
  if (t < 128) {
    float srow = rs[0][t] + rs[1][t];
    partial[(size_t)colg * 1024 + rowg * 128 + t] = srow;
  }
}

// ---------------------------------------------------------------- K3b: denom reduce
__global__ __launch_bounds__(256) void k_denom(const float* __restrict__ partial,
                                               float* __restrict__ rdenom) {
  const int row = blockIdx.x * 256 + threadIdx.x;
  float s = 0.f;
  for (int gI = 0; gI < NCOLG; ++gI) s += partial[(size_t)gI * 1024 + row];
  rdenom[row] = 1.0f / s;
}

// ---------------------------------------------------------------- K4: prob + PV GEMM (R3-proven)
// BM=128, BN=256, BK=64. grid (8 rowg, 2 colg, 32 splits) = 512 blocks, 4 waves.
// colg==0 blocks also write prob. A = bf16(exp(cos)*rdv) staged via LDS (swizzled),
// B = embT staged via global_load_lds with pre-swizzled source. 48 KB -> 3 blocks/CU.
__global__ __launch_bounds__(256, 2) void k_pv(const float* __restrict__ cosd,
                                               const unsigned short* __restrict__ embT,
                                               const float* __restrict__ rdenom,
                                               float* __restrict__ prob,
                                               float* __restrict__ kpart) {
  __shared__ unsigned short As[128 * 64];   // 16 KB, LDS[r][c]=G[r][c^(r&7)]
  __shared__ unsigned short Bs[256 * 64];   // 32 KB, same swizzle
  const int t = threadIdx.x;
  const int lane = t & 63, w = t >> 6;        // 4 waves
  const int wr = w >> 1, wc = w & 1;          // per-wave 64 rows x 128 d
  const int g = lane >> 4, l15 = lane & 15;
  const int rowg = blockIdx.x;                // 0..7
  const int colg = blockIdx.y;                // 0..1
  const int s = blockIdx.z;                   // 0..31
  const int t0 = s * 24 + (s < 4 ? s : 4);
  const int t1 = t0 + 24 + (s < 4 ? 1 : 0);

  // A staging: thread -> row ar = t>>1, interleave half ah = t&1 (float4s 2i+ah)
  const int ar = t >> 1, ah = t & 1;
  const int grow = rowg * 128 + ar;
  const float rdv = rdenom[grow];
  const float* cbase = cosd + (size_t)grow * VOC + ah * 4;
  float* pbase = prob + (size_t)grow * VOC + ah * 4;

  // B staging: gload i stages rows colg*256 + i*32 + w*8 + (lane>>3)
  const int brow_l = lane >> 3;
  const int bsl = (lane & 7) ^ brow_l;        // pre-swizzled source chunk

  f32x4 acc[4][8];
#pragma unroll
  for (int mi = 0; mi < 4; ++mi)
#pragma unroll
    for (int ni = 0; ni < 8; ++ni)
#pragma unroll
      for (int j = 0; j < 4; ++j) acc[mi][ni][j] = 0.0f;

  // prefetch first cos tile: float4 index j = 2i+ah -> v = 8i + 4ah
  float4 cc[8];
  {
    const float* cp = cbase + (size_t)t0 * 64;
#pragma unroll
    for (int i = 0; i < 8; ++i) cc[i] = *(const float4*)(cp + i * 8);
  }

  for (int kt = t0; kt < t1; ++kt) {
    const int v0 = kt * 64;
    __syncthreads();  // previous MFMA reads done -> LDS reusable

    // stage B: 8 x global_load_lds (linear LDS dest, pre-swizzled global src)
#pragma unroll
    for (int i = 0; i < 8; ++i) {
      gload16(embT + (size_t)(colg * 256 + i * 32 + w * 8 + brow_l) * VOC + v0 + bsl * 8,
              (const void*)(Bs + (i * 32 + w * 8) * 64));
    }

    // A: p = exp(cos)*rdv from prefetched regs; write prob (colg 0); pack to LDS
    float4 px[8];
#pragma unroll
    for (int i = 0; i < 8; ++i) {
      px[i].x = __expf(cc[i].x) * rdv;
      px[i].y = __expf(cc[i].y) * rdv;
      px[i].z = __expf(cc[i].z) * rdv;
      px[i].w = __expf(cc[i].w) * rdv;
    }
    if (colg == 0) {
#pragma unroll
      for (int i = 0; i < 8; ++i) *(float4*)(pbase + v0 + i * 8) = px[i];
    }
#pragma unroll
    for (int i = 0; i < 8; ++i) {
      bf16x4 b4;
      b4[0] = (short)f2bf(px[i].x);
      b4[1] = (short)f2bf(px[i].y);
      b4[2] = (short)f2bf(px[i].z);
      b4[3] = (short)f2bf(px[i].w);
      // float4 j=2i+ah -> chunk i, sub ah; swizzled slot i^(ar&7)
      *(bf16x4*)&As[ar * 64 + ((i ^ (ar & 7)) << 3) + ah * 4] = b4;
    }

    // prefetch next cos tile (completes at the barrier's vmcnt drain)
    if (kt + 1 < t1) {
      const float* cp = cbase + (size_t)(kt + 1) * 64;
#pragma unroll
      for (int i = 0; i < 8; ++i) cc[i] = *(const float4*)(cp + i * 8);
    }

    __syncthreads();  // B gloads + A ds_writes complete

    // MFMA: wave (wr,wc) owns rows [wr*64,+64) x d [wc*128,+128)
#pragma unroll
    for (int ks = 0; ks < 2; ++ks) {
      const int ch = (((ks * 4 + g) ^ (l15 & 7)) << 3);
      bf16x8 a[4];
#pragma unroll
      for (int mi = 0; mi < 4; ++mi)
        a[mi] = *(const bf16x8*)&As[(wr * 64 + mi * 16 + l15) * 64 + ch];
#pragma unroll
      for (int ni = 0; ni < 8; ++ni) {
        bf16x8 b = *(const bf16x8*)&Bs[(wc * 128 + ni * 16 + l15) * 64 + ch];
#pragma unroll
        for (int mi = 0; mi < 4; ++mi)
          acc[mi][ni] = __builtin_amdgcn_mfma_f32_16x16x32_bf16(a[mi], b, acc[mi][ni], 0, 0, 0);
      }
    }
  }

  // epilogue: kpart[s][row][d] (normalized — A carried rdv)
#pragma unroll
  for (int mi = 0; mi < 4; ++mi)
#pragma unroll
    for (int ni = 0; ni < 8; ++ni)
#pragma unroll
      for (int j = 0; j < 4; ++j)
        kpart[((size_t)s * 1024 + rowg * 128 + wr * 64 + mi * 16 + g * 4 + j) * TD +
              colg * 256 + wc * 128 + ni * 16 + l15] = acc[mi][ni][j];
}

// ---------------------------------------------------------------- K5: kw_out reduce (pure sum, float4)
__global__ __launch_bounds__(256) void k_kwout(const float* __restrict__ kpart,
                                               float* __restrict__ outp) {
  const int gid = blockIdx.x * 256 + threadIdx.x;   // 131072 threads x 4 elems
  float4 s = {0.f, 0.f, 0.f, 0.f};
#pragma unroll
  for (int sp = 0; sp < PV_S; ++sp) {
    float4 v = *(const float4*)(kpart + (size_t)sp * 524288 + gid * 4);
    s.x += v.x; s.y += v.y; s.z += v.z; s.w += v.w;
  }
  *(float4*)(outp + gid * 4) = s;
}

extern "C" void kernel_launch(void* const* d_in, const int* in_sizes, int n_in,
                              void* d_out, int out_size, void* d_ws, size_t ws_size,
                              hipStream_t stream) {
  const float* kw = (const float*)d_in[0];
  const float* Wp = (const float*)d_in[1];
  const float* bp = (const float*)d_in[2];
  const float* We = (const float*)d_in[3];
  float* out = (float*)d_out;
  char* ws = (char*)d_ws;

  unsigned short* embT = (unsigned short*)ws;                       // 50,593,792
  unsigned short* embn = (unsigned short*)(ws + 50593792);          // 50,593,792
  unsigned short* kwn = (unsigned short*)(ws + 101187584);          // 1,048,576
  float* rnormv = (float*)(ws + 102236160);                         // 197,632
  float* partial = (float*)(ws + 102433792);                        // 1,581,056
  float* rdenom = (float*)(ws + 104014848);                         // 4,096
  float* kpart = (float*)(ws + 104018944);                          // 67,108,864

  float* kwout = out;
  float* prob = out + 524288;
  float* cosd = out + 51118080;

  hipLaunchKernelGGL(k_proj, dim3(256), dim3(256), 0, stream, kw, Wp, bp, kwn);
  hipLaunchKernelGGL(k_norms, dim3(12352), dim3(256), 0, stream, We, rnormv);
  hipLaunchKernelGGL(k_transpose, dim3(6176), dim3(256), 0, stream, We, rnormv, embn, embT);
  hipLaunchKernelGGL(k_cos, dim3(3088), dim3(256), 0, stream, kwn, embn, cosd, partial);
  hipLaunchKernelGGL(k_denom, dim3(4), dim3(256), 0, stream, partial, rdenom);
  hipLaunchKernelGGL(k_pv, dim3(8, 2, PV_S), dim3(256), 0, stream, cosd, embT, rdenom,
                     prob, kpart);
  hipLaunchKernelGGL(k_kwout, dim3(512), dim3(256), 0, stream, kpart, kwout);
}

// Round 8
// 397.180 us; speedup vs baseline: 1.5729x; 1.2432x over previous
//
#include <hip/hip_runtime.h>

#define VOC 49408
#define TD 512
#define DM 768
#define NCOLG2 193   // VOC / 256  (k_cos col-groups)
#define PV_S 32

typedef __attribute__((ext_vector_type(8))) short bf16x8;
typedef __attribute__((ext_vector_type(4))) short bf16x4;
typedef __attribute__((ext_vector_type(4))) float f32x4;

__device__ __forceinline__ unsigned short f2bf(float f) {
  unsigned int u = __float_as_uint(f);
  u += 0x7fffu + ((u >> 16) & 1u);   // RNE
  return (unsigned short)(u >> 16);
}

__device__ __forceinline__ void gload16(const void* g, const void* l) {
  __builtin_amdgcn_global_load_lds(
      (const __attribute__((address_space(1))) void*)g,
      (__attribute__((address_space(3))) void*)l, 16, 0, 0);
}

// ---------------------------------------------------------------- K1: proj + normalize
__global__ __launch_bounds__(256) void k_proj(const float* __restrict__ kw,
                                              const float* __restrict__ Wp,
                                              const float* __restrict__ bp,
                                              unsigned short* __restrict__ kwn) {
  __shared__ float row_lds[4 * DM];
  __shared__ float rsum[4][4];
  __shared__ float rinv_s[4];
  const int t = threadIdx.x;
  const int rb = blockIdx.x * 4;
  for (int i = 0; i < 12; ++i) {
    int idx = i * 256 + t;
    row_lds[idx] = kw[(size_t)rb * DM + idx];
  }
  __syncthreads();
  float acc[4][2] = {};
  for (int m = 0; m < DM; ++m) {
    float w0 = Wp[m * TD + t];
    float w1 = Wp[m * TD + t + 256];
#pragma unroll
    for (int r = 0; r < 4; ++r) {
      float kv = row_lds[r * DM + m];
      acc[r][0] = fmaf(kv, w0, acc[r][0]);
      acc[r][1] = fmaf(kv, w1, acc[r][1]);
    }
  }
  const float b0 = bp[t], b1 = bp[t + 256];
  float p[4];
#pragma unroll
  for (int r = 0; r < 4; ++r) {
    acc[r][0] += b0;
    acc[r][1] += b1;
    p[r] = acc[r][0] * acc[r][0] + acc[r][1] * acc[r][1];
  }
#pragma unroll
  for (int off = 32; off; off >>= 1) {
#pragma unroll
    for (int r = 0; r < 4; ++r) p[r] += __shfl_down(p[r], off);
  }
  const int lane = t & 63, wv = t >> 6;
  if (lane == 0) {
#pragma unroll
    for (int r = 0; r < 4; ++r) rsum[r][wv] = p[r];
  }
  __syncthreads();
  if (t < 4) {
    float s = rsum[t][0] + rsum[t][1] + rsum[t][2] + rsum[t][3];
    rinv_s[t] = 1.0f / fmaxf(sqrtf(s), 1e-8f);
  }
  __syncthreads();
#pragma unroll
  for (int r = 0; r < 4; ++r) {
    float ri = rinv_s[r];
    kwn[(size_t)(rb + r) * TD + t] = f2bf(acc[r][0] * ri);
    kwn[(size_t)(rb + r) * TD + t + 256] = f2bf(acc[r][1] * ri);
  }
}

// ---------------------------------------------------------------- K2: one We pass -> embB (raw bf16) + rnormv
// grid 12352, block 256 (4 waves, 1 row each)
__global__ __launch_bounds__(256) void k_norms(const float* __restrict__ We,
                                               unsigned short* __restrict__ embB,
                                               float* __restrict__ rnormv) {
  const int t = threadIdx.x;
  const int lane = t & 63, w = t >> 6;
  const int v = blockIdx.x * 4 + w;
  const float* rowp = We + (size_t)v * TD;
  float4 a = *(const float4*)(rowp + lane * 8);
  float4 b = *(const float4*)(rowp + lane * 8 + 4);
  bf16x8 o;
  o[0] = (short)f2bf(a.x); o[1] = (short)f2bf(a.y);
  o[2] = (short)f2bf(a.z); o[3] = (short)f2bf(a.w);
  o[4] = (short)f2bf(b.x); o[5] = (short)f2bf(b.y);
  o[6] = (short)f2bf(b.z); o[7] = (short)f2bf(b.w);
  *(bf16x8*)(embB + (size_t)v * TD + lane * 8) = o;
  float ss = a.x * a.x + a.y * a.y + a.z * a.z + a.w * a.w +
             b.x * b.x + b.y * b.y + b.z * b.z + b.w * b.w;
#pragma unroll
  for (int off = 1; off < 64; off <<= 1) ss += __shfl_xor(ss, off);
  if (lane == 0) rnormv[v] = 1.0f / fmaxf(sqrtf(ss), 1e-8f);
}

// ---------------------------------------------------------------- K2b: transpose embB -> embT [d][v]
// grid (8 d-tiles, 772 v-tiles); d fastest so consecutive blocks share embB rows.
__global__ __launch_bounds__(256) void k_transpose(const unsigned short* __restrict__ embB,
                                                   unsigned short* __restrict__ embT) {
  __shared__ unsigned short tile[64 * 72];
  const int t = threadIdx.x;
  const int d0 = blockIdx.x * 64, v0 = blockIdx.y * 64;
#pragma unroll
  for (int p = 0; p < 2; ++p) {
    int vl = p * 32 + (t >> 3), ch = t & 7;
    *(bf16x8*)&tile[vl * 72 + ch * 8] =
        *(const bf16x8*)(embB + (size_t)(v0 + vl) * TD + d0 + ch * 8);
  }
  __syncthreads();
#pragma unroll
  for (int p = 0; p < 2; ++p) {
    int dl = p * 32 + (t >> 3), vch = t & 7;
    bf16x8 o;
#pragma unroll
    for (int i = 0; i < 8; ++i) o[i] = (short)tile[(vch * 8 + i) * 72 + dl];
    *(bf16x8*)(embT + (size_t)(d0 + dl) * VOC + v0 + vch * 8) = o;
  }
}

// ---------------------------------------------------------------- K3: cos GEMM (256x256 tile) + sumexp partials
// BM=256, BN=256, BK=64. grid (4 rowg, 193 colg), 512 threads = 8 waves (wave: 64r x 128c).
// B = raw embB; normalization applied in epilogue via rnormv[col]. LDS 66 KB -> 2 blocks/CU.
__global__ __launch_bounds__(512, 2) void k_cos(const unsigned short* __restrict__ kwn,
                                                const unsigned short* __restrict__ embB,
                                                const float* __restrict__ rnormv,
                                                float* __restrict__ cosd,
                                                float* __restrict__ partial) {
  __shared__ unsigned short As[256 * 64];   // 32 KB, LDS[r][c8]=G[r][c8^(r&7)]
  __shared__ unsigned short Bs[256 * 64];   // 32 KB, same swizzle
  __shared__ float rs[2][256];
  const int t = threadIdx.x;
  const int lane = t & 63, w = t >> 6;       // 8 waves
  const int wr = w & 3, wc = w >> 2;         // rows wr*64.., cols wc*128..
  const int g = lane >> 4, l15 = lane & 15;
  const int rowg = blockIdx.x;               // 0..3
  const int colg = blockIdx.y;               // 0..192

  const int rl = lane >> 3;
  const int bsl = (lane & 7) ^ rl;           // pre-swizzled source chunk

  f32x4 acc[4][8];
#pragma unroll
  for (int mi = 0; mi < 4; ++mi)
#pragma unroll
    for (int ni = 0; ni < 8; ++ni)
#pragma unroll
      for (int j = 0; j < 4; ++j) acc[mi][ni][j] = 0.0f;

  for (int kt = 0; kt < 8; ++kt) {
#pragma unroll
    for (int i = 0; i < 4; ++i) {
      gload16(kwn + (size_t)(rowg * 256 + i * 64 + w * 8 + rl) * TD + kt * 64 + bsl * 8,
              (const void*)(As + (i * 64 + w * 8) * 64));
      gload16(embB + (size_t)(colg * 256 + i * 64 + w * 8 + rl) * TD + kt * 64 + bsl * 8,
              (const void*)(Bs + (i * 64 + w * 8) * 64));
    }
    __syncthreads();
#pragma unroll
    for (int ks = 0; ks < 2; ++ks) {
      const int ch = (((ks * 4 + g) ^ (l15 & 7)) << 3);
      bf16x8 a[4];
#pragma unroll
      for (int mi = 0; mi < 4; ++mi)
        a[mi] = *(const bf16x8*)&As[(wr * 64 + mi * 16 + l15) * 64 + ch];
#pragma unroll
      for (int ni = 0; ni < 8; ++ni) {
        bf16x8 b = *(const bf16x8*)&Bs[(wc * 128 + ni * 16 + l15) * 64 + ch];
#pragma unroll
        for (int mi = 0; mi < 4; ++mi)
          acc[mi][ni] = __builtin_amdgcn_mfma_f32_16x16x32_bf16(a[mi], b, acc[mi][ni], 0, 0, 0);
      }
    }
    __syncthreads();
  }

  // epilogue: scale by rnormv[col], write cos, per-row sumexp
  const size_t rowbase = (size_t)rowg * 256 + wr * 64;
  const int colbase = colg * 256 + wc * 128;
  float rnv[8];
#pragma unroll
  for (int ni = 0; ni < 8; ++ni) rnv[ni] = rnormv[colbase + ni * 16 + l15];
#pragma unroll
  for (int mi = 0; mi < 4; ++mi) {
    float es[4] = {0.f, 0.f, 0.f, 0.f};
#pragma unroll
    for (int ni = 0; ni < 8; ++ni) {
#pragma unroll
      for (int j = 0; j < 4; ++j) {
        float c = acc[mi][ni][j] * rnv[ni];
        cosd[(rowbase + mi * 16 + g * 4 + j) * VOC + colbase + ni * 16 + l15] = c;
        es[j] += __expf(c);
      }
    }
#pragma unroll
    for (int j = 0; j < 4; ++j) {
      float e = es[j];
      e += __shfl_xor(e, 1);
      e += __shfl_xor(e, 2);
      e += __shfl_xor(e, 4);
      e += __shfl_xor(e, 8);
      if (l15 == 0) rs[wc][wr * 64 + mi * 16 + g * 4 + j] = e;
    }
  }
  __syncthreads();
  if (t < 256) {
    float srow = rs[0][t] + rs[1][t];
    partial[(size_t)colg * 1024 + rowg * 256 + t] = srow;
  }
}

// ---------------------------------------------------------------- K3b: denom reduce (1 wave per row)
// grid 256, block 256 = 4 waves; wave handles one row, lanes stride col-groups.
__global__ __launch_bounds__(256) void k_denom(const float* __restrict__ partial,
                                               float* __restrict__ rdenom) {
  const int t = threadIdx.x;
  const int lane = t & 63, w = t >> 6;
  const int row = blockIdx.x * 4 + w;
  float s = 0.f;
  for (int c = lane; c < NCOLG2; c += 64) s += partial[(size_t)c * 1024 + row];
#pragma unroll
  for (int off = 1; off < 64; off <<= 1) s += __shfl_xor(s, off);
  if (lane == 0) rdenom[row] = 1.0f / s;
}

// ---------------------------------------------------------------- K4: prob + PV GEMM (R3-proven)
// BM=128, BN=256, BK=64. grid (8 rowg, 2 colg, 32 splits) = 512 blocks, 4 waves.
__global__ __launch_bounds__(256, 2) void k_pv(const float* __restrict__ cosd,
                                               const unsigned short* __restrict__ embT,
                                               const float* __restrict__ rdenom,
                                               float* __restrict__ prob,
                                               float* __restrict__ kpart) {
  __shared__ unsigned short As[128 * 64];   // 16 KB, LDS[r][c]=G[r][c^(r&7)]
  __shared__ unsigned short Bs[256 * 64];   // 32 KB, same swizzle
  const int t = threadIdx.x;
  const int lane = t & 63, w = t >> 6;        // 4 waves
  const int wr = w >> 1, wc = w & 1;          // per-wave 64 rows x 128 d
  const int g = lane >> 4, l15 = lane & 15;
  const int rowg = blockIdx.x;                // 0..7
  const int colg = blockIdx.y;                // 0..1
  const int s = blockIdx.z;                   // 0..31
  const int t0 = s * 24 + (s < 4 ? s : 4);
  const int t1 = t0 + 24 + (s < 4 ? 1 : 0);

  const int ar = t >> 1, ah = t & 1;
  const int grow = rowg * 128 + ar;
  const float rdv = rdenom[grow];
  const float* cbase = cosd + (size_t)grow * VOC + ah * 4;
  float* pbase = prob + (size_t)grow * VOC + ah * 4;

  const int brow_l = lane >> 3;
  const int bsl = (lane & 7) ^ brow_l;        // pre-swizzled source chunk

  f32x4 acc[4][8];
#pragma unroll
  for (int mi = 0; mi < 4; ++mi)
#pragma unroll
    for (int ni = 0; ni < 8; ++ni)
#pragma unroll
      for (int j = 0; j < 4; ++j) acc[mi][ni][j] = 0.0f;

  float4 cc[8];
  {
    const float* cp = cbase + (size_t)t0 * 64;
#pragma unroll
    for (int i = 0; i < 8; ++i) cc[i] = *(const float4*)(cp + i * 8);
  }

  for (int kt = t0; kt < t1; ++kt) {
    const int v0 = kt * 64;
    __syncthreads();

#pragma unroll
    for (int i = 0; i < 8; ++i) {
      gload16(embT + (size_t)(colg * 256 + i * 32 + w * 8 + brow_l) * VOC + v0 + bsl * 8,
              (const void*)(Bs + (i * 32 + w * 8) * 64));
    }

    float4 px[8];
#pragma unroll
    for (int i = 0; i < 8; ++i) {
      px[i].x = __expf(cc[i].x) * rdv;
      px[i].y = __expf(cc[i].y) * rdv;
      px[i].z = __expf(cc[i].z) * rdv;
      px[i].w = __expf(cc[i].w) * rdv;
    }
    if (colg == 0) {
#pragma unroll
      for (int i = 0; i < 8; ++i) *(float4*)(pbase + v0 + i * 8) = px[i];
    }
#pragma unroll
    for (int i = 0; i < 8; ++i) {
      bf16x4 b4;
      b4[0] = (short)f2bf(px[i].x);
      b4[1] = (short)f2bf(px[i].y);
      b4[2] = (short)f2bf(px[i].z);
      b4[3] = (short)f2bf(px[i].w);
      *(bf16x4*)&As[ar * 64 + ((i ^ (ar & 7)) << 3) + ah * 4] = b4;
    }

    if (kt + 1 < t1) {
      const float* cp = cbase + (size_t)(kt + 1) * 64;
#pragma unroll
      for (int i = 0; i < 8; ++i) cc[i] = *(const float4*)(cp + i * 8);
    }

    __syncthreads();

#pragma unroll
    for (int ks = 0; ks < 2; ++ks) {
      const int ch = (((ks * 4 + g) ^ (l15 & 7)) << 3);
      bf16x8 a[4];
#pragma unroll
      for (int mi = 0; mi < 4; ++mi)
        a[mi] = *(const bf16x8*)&As[(wr * 64 + mi * 16 + l15) * 64 + ch];
#pragma unroll
      for (int ni = 0; ni < 8; ++ni) {
        bf16x8 b = *(const bf16x8*)&Bs[(wc * 128 + ni * 16 + l15) * 64 + ch];
#pragma unroll
        for (int mi = 0; mi < 4; ++mi)
          acc[mi][ni] = __builtin_amdgcn_mfma_f32_16x16x32_bf16(a[mi], b, acc[mi][ni], 0, 0, 0);
      }
    }
  }

#pragma unroll
  for (int mi = 0; mi < 4; ++mi)
#pragma unroll
    for (int ni = 0; ni < 8; ++ni)
#pragma unroll
      for (int j = 0; j < 4; ++j)
        kpart[((size_t)s * 1024 + rowg * 128 + wr * 64 + mi * 16 + g * 4 + j) * TD +
              colg * 256 + wc * 128 + ni * 16 + l15] = acc[mi][ni][j];
}

// ---------------------------------------------------------------- K5: kw_out reduce (pure sum, float4)
__global__ __launch_bounds__(256) void k_kwout(const float* __restrict__ kpart,
                                               float* __restrict__ outp) {
  const int gid = blockIdx.x * 256 + threadIdx.x;
  float4 s = {0.f, 0.f, 0.f, 0.f};
#pragma unroll
  for (int sp = 0; sp < PV_S; ++sp) {
    float4 v = *(const float4*)(kpart + (size_t)sp * 524288 + gid * 4);
    s.x += v.x; s.y += v.y; s.z += v.z; s.w += v.w;
  }
  *(float4*)(outp + gid * 4) = s;
}

extern "C" void kernel_launch(void* const* d_in, const int* in_sizes, int n_in,
                              void* d_out, int out_size, void* d_ws, size_t ws_size,
                              hipStream_t stream) {
  const float* kw = (const float*)d_in[0];
  const float* Wp = (const float*)d_in[1];
  const float* bp = (const float*)d_in[2];
  const float* We = (const float*)d_in[3];
  float* out = (float*)d_out;
  char* ws = (char*)d_ws;

  unsigned short* embT = (unsigned short*)ws;                       // 50,593,792
  unsigned short* embB = (unsigned short*)(ws + 50593792);          // 50,593,792
  unsigned short* kwn = (unsigned short*)(ws + 101187584);          // 1,048,576
  float* rnormv = (float*)(ws + 102236160);                         // 197,632
  float* partial = (float*)(ws + 102433792);                        // 790,528
  float* rdenom = (float*)(ws + 103224320);                         // 4,096
  float* kpart = (float*)(ws + 103228416);                          // 67,108,864

  float* kwout = out;
  float* prob = out + 524288;
  float* cosd = out + 51118080;

  hipLaunchKernelGGL(k_proj, dim3(256), dim3(256), 0, stream, kw, Wp, bp, kwn);
  hipLaunchKernelGGL(k_norms, dim3(12352), dim3(256), 0, stream, We, embB, rnormv);
  hipLaunchKernelGGL(k_transpose, dim3(8, 772), dim3(256), 0, stream, embB, embT);
  hipLaunchKernelGGL(k_cos, dim3(4, NCOLG2), dim3(512), 0, stream, kwn, embB, rnormv,
                     cosd, partial);
  hipLaunchKernelGGL(k_denom, dim3(256), dim3(256), 0, stream, partial, rdenom);
  hipLaunchKernelGGL(k_pv, dim3(8, 2, PV_S), dim3(256), 0, stream, cosd, embT, rdenom,
                     prob, kpart);
  hipLaunchKernelGGL(k_kwout, dim3(512), dim3(256), 0, stream, kpart, kwout);
}

// Round 9
// 377.746 us; speedup vs baseline: 1.6538x; 1.0514x over previous
//
#include <hip/hip_runtime.h>

#define VOC 49408
#define TD 512
#define DM 768
#define NCOLG2 193   // VOC / 256  (k_cos col-groups)
#define PV_S 32

typedef __attribute__((ext_vector_type(8))) short bf16x8;
typedef __attribute__((ext_vector_type(4))) short bf16x4;
typedef __attribute__((ext_vector_type(4))) float f32x4;

__device__ __forceinline__ unsigned short f2bf(float f) {
  unsigned int u = __float_as_uint(f);
  u += 0x7fffu + ((u >> 16) & 1u);   // RNE
  return (unsigned short)(u >> 16);
}

__device__ __forceinline__ void gload16(const void* g, const void* l) {
  __builtin_amdgcn_global_load_lds(
      (const __attribute__((address_space(1))) void*)g,
      (__attribute__((address_space(3))) void*)l, 16, 0, 0);
}

// ---------------------------------------------------------------- K1: proj + normalize
__global__ __launch_bounds__(256) void k_proj(const float* __restrict__ kw,
                                              const float* __restrict__ Wp,
                                              const float* __restrict__ bp,
                                              unsigned short* __restrict__ kwn) {
  __shared__ float row_lds[4 * DM];
  __shared__ float rsum[4][4];
  __shared__ float rinv_s[4];
  const int t = threadIdx.x;
  const int rb = blockIdx.x * 4;
  for (int i = 0; i < 12; ++i) {
    int idx = i * 256 + t;
    row_lds[idx] = kw[(size_t)rb * DM + idx];
  }
  __syncthreads();
  float acc[4][2] = {};
  for (int m = 0; m < DM; ++m) {
    float w0 = Wp[m * TD + t];
    float w1 = Wp[m * TD + t + 256];
#pragma unroll
    for (int r = 0; r < 4; ++r) {
      float kv = row_lds[r * DM + m];
      acc[r][0] = fmaf(kv, w0, acc[r][0]);
      acc[r][1] = fmaf(kv, w1, acc[r][1]);
    }
  }
  const float b0 = bp[t], b1 = bp[t + 256];
  float p[4];
#pragma unroll
  for (int r = 0; r < 4; ++r) {
    acc[r][0] += b0;
    acc[r][1] += b1;
    p[r] = acc[r][0] * acc[r][0] + acc[r][1] * acc[r][1];
  }
#pragma unroll
  for (int off = 32; off; off >>= 1) {
#pragma unroll
    for (int r = 0; r < 4; ++r) p[r] += __shfl_down(p[r], off);
  }
  const int lane = t & 63, wv = t >> 6;
  if (lane == 0) {
#pragma unroll
    for (int r = 0; r < 4; ++r) rsum[r][wv] = p[r];
  }
  __syncthreads();
  if (t < 4) {
    float s = rsum[t][0] + rsum[t][1] + rsum[t][2] + rsum[t][3];
    rinv_s[t] = 1.0f / fmaxf(sqrtf(s), 1e-8f);
  }
  __syncthreads();
#pragma unroll
  for (int r = 0; r < 4; ++r) {
    float ri = rinv_s[r];
    kwn[(size_t)(rb + r) * TD + t] = f2bf(acc[r][0] * ri);
    kwn[(size_t)(rb + r) * TD + t + 256] = f2bf(acc[r][1] * ri);
  }
}

// ---------------------------------------------------------------- K2: one We pass -> embB (raw bf16) + rnormv
__global__ __launch_bounds__(256) void k_norms(const float* __restrict__ We,
                                               unsigned short* __restrict__ embB,
                                               float* __restrict__ rnormv) {
  const int t = threadIdx.x;
  const int lane = t & 63, w = t >> 6;
  const int v = blockIdx.x * 4 + w;
  const float* rowp = We + (size_t)v * TD;
  float4 a = *(const float4*)(rowp + lane * 8);
  float4 b = *(const float4*)(rowp + lane * 8 + 4);
  bf16x8 o;
  o[0] = (short)f2bf(a.x); o[1] = (short)f2bf(a.y);
  o[2] = (short)f2bf(a.z); o[3] = (short)f2bf(a.w);
  o[4] = (short)f2bf(b.x); o[5] = (short)f2bf(b.y);
  o[6] = (short)f2bf(b.z); o[7] = (short)f2bf(b.w);
  *(bf16x8*)(embB + (size_t)v * TD + lane * 8) = o;
  float ss = a.x * a.x + a.y * a.y + a.z * a.z + a.w * a.w +
             b.x * b.x + b.y * b.y + b.z * b.z + b.w * b.w;
#pragma unroll
  for (int off = 1; off < 64; off <<= 1) ss += __shfl_xor(ss, off);
  if (lane == 0) rnormv[v] = 1.0f / fmaxf(sqrtf(ss), 1e-8f);
}

// ---------------------------------------------------------------- K2b: transpose embB -> embT [d][v]
__global__ __launch_bounds__(256) void k_transpose(const unsigned short* __restrict__ embB,
                                                   unsigned short* __restrict__ embT) {
  __shared__ unsigned short tile[64 * 72];
  const int t = threadIdx.x;
  const int d0 = blockIdx.x * 64, v0 = blockIdx.y * 64;
#pragma unroll
  for (int p = 0; p < 2; ++p) {
    int vl = p * 32 + (t >> 3), ch = t & 7;
    *(bf16x8*)&tile[vl * 72 + ch * 8] =
        *(const bf16x8*)(embB + (size_t)(v0 + vl) * TD + d0 + ch * 8);
  }
  __syncthreads();
#pragma unroll
  for (int p = 0; p < 2; ++p) {
    int dl = p * 32 + (t >> 3), vch = t & 7;
    bf16x8 o;
#pragma unroll
    for (int i = 0; i < 8; ++i) o[i] = (short)tile[(vch * 8 + i) * 72 + dl];
    *(bf16x8*)(embT + (size_t)(d0 + dl) * VOC + v0 + vch * 8) = o;
  }
}

// ---------------------------------------------------------------- K3: cos GEMM (256x256, dbuf 1-barrier) + sumexp
// BM=256, BN=256, BK=64. grid (4 rowg, 193 colg), 512 thr = 8 waves (64r x 128c each).
// LDS 128 KiB double-buffered; stage(kt+1) overlaps MFMA(kt); one barrier per step.
__global__ __launch_bounds__(512, 2) void k_cos(const unsigned short* __restrict__ kwn,
                                                const unsigned short* __restrict__ embB,
                                                const float* __restrict__ rnormv,
                                                float* __restrict__ cosd,
                                                float* __restrict__ partial) {
  __shared__ unsigned short smem[2][2][256 * 64];   // [buf][op A/B] 128 KiB
  const int t = threadIdx.x;
  const int lane = t & 63, w = t >> 6;       // 8 waves
  const int wr = w & 3, wc = w >> 2;         // rows wr*64.., cols wc*128..
  const int g = lane >> 4, l15 = lane & 15;
  const int rowg = blockIdx.x;               // 0..3
  const int colg = blockIdx.y;               // 0..192

  const int rl = lane >> 3;
  const int bsl = (lane & 7) ^ rl;           // pre-swizzled source chunk

  f32x4 acc[4][8];
#pragma unroll
  for (int mi = 0; mi < 4; ++mi)
#pragma unroll
    for (int ni = 0; ni < 8; ++ni)
#pragma unroll
      for (int j = 0; j < 4; ++j) acc[mi][ni][j] = 0.0f;

  const unsigned short* Ag = kwn + (size_t)(rowg * 256 + w * 8 + rl) * TD + bsl * 8;
  const unsigned short* Bg = embB + (size_t)(colg * 256 + w * 8 + rl) * TD + bsl * 8;

  // prologue: stage tile 0 into buf 0
#pragma unroll
  for (int i = 0; i < 4; ++i) {
    gload16(Ag + (size_t)(i * 64) * TD, (const void*)(&smem[0][0][(i * 64 + w * 8) * 64]));
    gload16(Bg + (size_t)(i * 64) * TD, (const void*)(&smem[0][1][(i * 64 + w * 8) * 64]));
  }
  __syncthreads();

  for (int kt = 0; kt < 8; ++kt) {
    const int buf = kt & 1;
    if (kt < 7) {
#pragma unroll
      for (int i = 0; i < 4; ++i) {
        gload16(Ag + (size_t)(i * 64) * TD + (kt + 1) * 64,
                (const void*)(&smem[buf ^ 1][0][(i * 64 + w * 8) * 64]));
        gload16(Bg + (size_t)(i * 64) * TD + (kt + 1) * 64,
                (const void*)(&smem[buf ^ 1][1][(i * 64 + w * 8) * 64]));
      }
    }
#pragma unroll
    for (int ks = 0; ks < 2; ++ks) {
      const int ch = (((ks * 4 + g) ^ (l15 & 7)) << 3);
      bf16x8 a[4];
#pragma unroll
      for (int mi = 0; mi < 4; ++mi)
        a[mi] = *(const bf16x8*)&smem[buf][0][(wr * 64 + mi * 16 + l15) * 64 + ch];
#pragma unroll
      for (int ni = 0; ni < 8; ++ni) {
        bf16x8 b = *(const bf16x8*)&smem[buf][1][(wc * 128 + ni * 16 + l15) * 64 + ch];
#pragma unroll
        for (int mi = 0; mi < 4; ++mi)
          acc[mi][ni] = __builtin_amdgcn_mfma_f32_16x16x32_bf16(a[mi], b, acc[mi][ni], 0, 0, 0);
      }
    }
    __syncthreads();   // drains next-tile gloads + syncs buffer swap
  }

  // epilogue: scale by rnormv[col], write cos, per-row sumexp (rs aliases smem)
  float (*rs)[256] = (float(*)[256]) & smem[0][0][0];
  const size_t rowbase = (size_t)rowg * 256 + wr * 64;
  const int colbase = colg * 256 + wc * 128;
  float rnv[8];
#pragma unroll
  for (int ni = 0; ni < 8; ++ni) rnv[ni] = rnormv[colbase + ni * 16 + l15];
#pragma unroll
  for (int mi = 0; mi < 4; ++mi) {
    float es[4] = {0.f, 0.f, 0.f, 0.f};
#pragma unroll
    for (int ni = 0; ni < 8; ++ni) {
#pragma unroll
      for (int j = 0; j < 4; ++j) {
        float c = acc[mi][ni][j] * rnv[ni];
        cosd[(rowbase + mi * 16 + g * 4 + j) * VOC + colbase + ni * 16 + l15] = c;
        es[j] += __expf(c);
      }
    }
#pragma unroll
    for (int j = 0; j < 4; ++j) {
      float e = es[j];
      e += __shfl_xor(e, 1);
      e += __shfl_xor(e, 2);
      e += __shfl_xor(e, 4);
      e += __shfl_xor(e, 8);
      if (l15 == 0) rs[wc][wr * 64 + mi * 16 + g * 4 + j] = e;
    }
  }
  __syncthreads();
  if (t < 256) {
    float srow = rs[0][t] + rs[1][t];
    partial[(size_t)colg * 1024 + rowg * 256 + t] = srow;
  }
}

// ---------------------------------------------------------------- K3b: denom reduce (1 wave per row)
__global__ __launch_bounds__(256) void k_denom(const float* __restrict__ partial,
                                               float* __restrict__ rdenom) {
  const int t = threadIdx.x;
  const int lane = t & 63, w = t >> 6;
  const int row = blockIdx.x * 4 + w;
  float s = 0.f;
  for (int c = lane; c < NCOLG2; c += 64) s += partial[(size_t)c * 1024 + row];
#pragma unroll
  for (int off = 1; off < 64; off <<= 1) s += __shfl_xor(s, off);
  if (lane == 0) rdenom[row] = 1.0f / s;
}

// ---------------------------------------------------------------- K4: prob + PV GEMM (256x256, dbuf 1-barrier)
// BM=256, BN=256, BK=64. grid (4 rowg, 2 colg, 32 splits) = 256 blocks, 512 thr/8 waves.
// A = bf16(exp(cos)*rdv) ds_written to buf^1 during MFMA(kt); B = embT gload16 dbuf.
// prob tile kt written by the colg == (kt&1) block (load balance).
__global__ __launch_bounds__(512, 2) void k_pv(const float* __restrict__ cosd,
                                               const unsigned short* __restrict__ embT,
                                               const float* __restrict__ rdenom,
                                               float* __restrict__ prob,
                                               float* __restrict__ kpart) {
  __shared__ unsigned short smem[2][2][256 * 64];   // [buf][A/B] 128 KiB
  const int t = threadIdx.x;
  const int lane = t & 63, w = t >> 6;        // 8 waves
  const int wr = w & 3, wc = w >> 2;          // per-wave 64 rows x 128 d
  const int g = lane >> 4, l15 = lane & 15;
  const int rowg = blockIdx.x;                // 0..3
  const int colg = blockIdx.y;                // 0..1
  const int s = blockIdx.z;                   // 0..31
  const int t0 = s * 24 + (s < 4 ? s : 4);
  const int t1 = t0 + 24 + (s < 4 ? 1 : 0);

  // A path: thread owns row ar (0..255), half ah; 8 float4 chunks (v = 8i+4ah)
  const int ar = t >> 1, ah = t & 1;
  const int grow = rowg * 256 + ar;
  const float rdv = rdenom[grow];
  const float* cbase = cosd + (size_t)grow * VOC + ah * 4;
  float* pbase = prob + (size_t)grow * VOC + ah * 4;

  // B staging lane constants
  const int rl = lane >> 3;
  const int bsl = (lane & 7) ^ rl;            // pre-swizzled source chunk

  f32x4 acc[4][8];
#pragma unroll
  for (int mi = 0; mi < 4; ++mi)
#pragma unroll
    for (int ni = 0; ni < 8; ++ni)
#pragma unroll
      for (int j = 0; j < 4; ++j) acc[mi][ni][j] = 0.0f;

  // helper lambdas inlined manually: stage B(kt)->buf, A(kt)->buf from cc regs
  float4 cc[8];
  {
    const float* cp = cbase + (size_t)t0 * 64;
#pragma unroll
    for (int i = 0; i < 8; ++i) cc[i] = *(const float4*)(cp + i * 8);
  }

  // prologue: stage tile t0 into buf 0
#pragma unroll
  for (int i = 0; i < 4; ++i) {
    gload16(embT + (size_t)(colg * 256 + i * 64 + w * 8 + rl) * VOC + t0 * 64 + bsl * 8,
            (const void*)(&smem[0][1][(i * 64 + w * 8) * 64]));
  }
  {
    const bool wp = (colg == (t0 & 1));
#pragma unroll
    for (int i = 0; i < 8; ++i) {
      float4 px;
      px.x = __expf(cc[i].x) * rdv;
      px.y = __expf(cc[i].y) * rdv;
      px.z = __expf(cc[i].z) * rdv;
      px.w = __expf(cc[i].w) * rdv;
      if (wp) *(float4*)(pbase + (size_t)t0 * 64 + i * 8) = px;
      bf16x4 b4;
      b4[0] = (short)f2bf(px.x);
      b4[1] = (short)f2bf(px.y);
      b4[2] = (short)f2bf(px.z);
      b4[3] = (short)f2bf(px.w);
      *(bf16x4*)&smem[0][0][ar * 64 + ((i ^ (ar & 7)) << 3) + ah * 4] = b4;
    }
  }
  if (t0 + 1 < t1) {
    const float* cp = cbase + (size_t)(t0 + 1) * 64;
#pragma unroll
    for (int i = 0; i < 8; ++i) cc[i] = *(const float4*)(cp + i * 8);
  }
  __syncthreads();

  for (int kt = t0; kt < t1; ++kt) {
    const int buf = (kt - t0) & 1;
    if (kt + 1 < t1) {
      // stage B(kt+1)
#pragma unroll
      for (int i = 0; i < 4; ++i) {
        gload16(embT + (size_t)(colg * 256 + i * 64 + w * 8 + rl) * VOC + (kt + 1) * 64 + bsl * 8,
                (const void*)(&smem[buf ^ 1][1][(i * 64 + w * 8) * 64]));
      }
      // A(kt+1): exp from cc regs; prob write (balanced); ds_write to buf^1
      const bool wp = (colg == ((kt + 1) & 1));
#pragma unroll
      for (int i = 0; i < 8; ++i) {
        float4 px;
        px.x = __expf(cc[i].x) * rdv;
        px.y = __expf(cc[i].y) * rdv;
        px.z = __expf(cc[i].z) * rdv;
        px.w = __expf(cc[i].w) * rdv;
        if (wp) *(float4*)(pbase + (size_t)(kt + 1) * 64 + i * 8) = px;
        bf16x4 b4;
        b4[0] = (short)f2bf(px.x);
        b4[1] = (short)f2bf(px.y);
        b4[2] = (short)f2bf(px.z);
        b4[3] = (short)f2bf(px.w);
        *(bf16x4*)&smem[buf ^ 1][0][ar * 64 + ((i ^ (ar & 7)) << 3) + ah * 4] = b4;
      }
      // prefetch cos regs for kt+2
      if (kt + 2 < t1) {
        const float* cp = cbase + (size_t)(kt + 2) * 64;
#pragma unroll
        for (int i = 0; i < 8; ++i) cc[i] = *(const float4*)(cp + i * 8);
      }
    }
    // MFMA(kt) from buf
#pragma unroll
    for (int ks = 0; ks < 2; ++ks) {
      const int ch = (((ks * 4 + g) ^ (l15 & 7)) << 3);
      bf16x8 a[4];
#pragma unroll
      for (int mi = 0; mi < 4; ++mi)
        a[mi] = *(const bf16x8*)&smem[buf][0][(wr * 64 + mi * 16 + l15) * 64 + ch];
#pragma unroll
      for (int ni = 0; ni < 8; ++ni) {
        bf16x8 b = *(const bf16x8*)&smem[buf][1][(wc * 128 + ni * 16 + l15) * 64 + ch];
#pragma unroll
        for (int mi = 0; mi < 4; ++mi)
          acc[mi][ni] = __builtin_amdgcn_mfma_f32_16x16x32_bf16(a[mi], b, acc[mi][ni], 0, 0, 0);
      }
    }
    __syncthreads();   // drains buf^1 writes (gloads + ds_writes) + swap
  }

  // epilogue: kpart[s][row][d] (normalized — A carried rdv)
#pragma unroll
  for (int mi = 0; mi < 4; ++mi)
#pragma unroll
    for (int ni = 0; ni < 8; ++ni)
#pragma unroll
      for (int j = 0; j < 4; ++j)
        kpart[((size_t)s * 1024 + rowg * 256 + wr * 64 + mi * 16 + g * 4 + j) * TD +
              colg * 256 + wc * 128 + ni * 16 + l15] = acc[mi][ni][j];
}

// ---------------------------------------------------------------- K5: kw_out reduce (pure sum, float4)
__global__ __launch_bounds__(256) void k_kwout(const float* __restrict__ kpart,
                                               float* __restrict__ outp) {
  const int gid = blockIdx.x * 256 + threadIdx.x;
  float4 s = {0.f, 0.f, 0.f, 0.f};
#pragma unroll
  for (int sp = 0; sp < PV_S; ++sp) {
    float4 v = *(const float4*)(kpart + (size_t)sp * 524288 + gid * 4);
    s.x += v.x; s.y += v.y; s.z += v.z; s.w += v.w;
  }
  *(float4*)(outp + gid * 4) = s;
}

extern "C" void kernel_launch(void* const* d_in, const int* in_sizes, int n_in,
                              void* d_out, int out_size, void* d_ws, size_t ws_size,
                              hipStream_t stream) {
  const float* kw = (const float*)d_in[0];
  const float* Wp = (const float*)d_in[1];
  const float* bp = (const float*)d_in[2];
  const float* We = (const float*)d_in[3];
  float* out = (float*)d_out;
  char* ws = (char*)d_ws;

  unsigned short* embT = (unsigned short*)ws;                       // 50,593,792
  unsigned short* embB = (unsigned short*)(ws + 50593792);          // 50,593,792
  unsigned short* kwn = (unsigned short*)(ws + 101187584);          // 1,048,576
  float* rnormv = (float*)(ws + 102236160);                         // 197,632
  float* partial = (float*)(ws + 102433792);                        // 790,528
  float* rdenom = (float*)(ws + 103224320);                         // 4,096
  float* kpart = (float*)(ws + 103228416);                          // 67,108,864

  float* kwout = out;
  float* prob = out + 524288;
  float* cosd = out + 51118080;

  hipLaunchKernelGGL(k_proj, dim3(256), dim3(256), 0, stream, kw, Wp, bp, kwn);
  hipLaunchKernelGGL(k_norms, dim3(12352), dim3(256), 0, stream, We, embB, rnormv);
  hipLaunchKernelGGL(k_transpose, dim3(8, 772), dim3(256), 0, stream, embB, embT);
  hipLaunchKernelGGL(k_cos, dim3(4, NCOLG2), dim3(512), 0, stream, kwn, embB, rnormv,
                     cosd, partial);
  hipLaunchKernelGGL(k_denom, dim3(256), dim3(256), 0, stream, partial, rdenom);
  hipLaunchKernelGGL(k_pv, dim3(4, 2, PV_S), dim3(512), 0, stream, cosd, embT, rdenom,
                     prob, kpart);
  hipLaunchKernelGGL(k_kwout, dim3(512), dim3(256), 0, stream, kpart, kwout);
}